// Round 4
// baseline (386.384 us; speedup 1.0000x reference)
//
#include <hip/hip_runtime.h>

// SoftDecisionTree fused pipeline for MI355X (gfx950).
// Inputs: x[16384,2048] f32, y[16384,1000] f32 one-hot, W[255,2048] f32,
//         b[255] f32, beta[255] f32, leaf_params[256,1000] f32
// Output: [loss(1) | output(16384*1000)] f32
//
// gemm_tree v4: direct-to-register GEMM at 2x the occupancy.
//  - r1/r2/r3 all sat at ~8 waves/CU (2 waves/SIMD, Occupancy ~20%) and all
//    landed at 91-111 us regardless of K-loop structure: classic latency x TLP
//    limit (per-CU in-flight bytes ~8 KB -> ~23 GB/s/CU, exactly as measured).
//  - v4: 512 threads/block (8 waves), wave tile 32x32, launch_bounds(512,4)
//    -> 16 waves/CU, 4 waves/SIMD. Stage regs drop to 24 VGPR so the explicit
//    2-deep pipeline survives register allocation (~100 VGPR total).
//  - Same 512 blocks / BM=32: B L2 traffic unchanged, accumulation order
//    bit-identical to the verified r1-r3 kernels (absmax canary 0.04762268).

typedef __attribute__((ext_vector_type(8))) short short8;
typedef __attribute__((ext_vector_type(4))) float f32x4;

#define DIM 2048
#define NCLS 1000
#define NINNER 255
#define NPAD 256
#define BM 32        // rows per block (8 waves: wave tile 32x32 covers N=256)

__device__ __forceinline__ unsigned cvt2bf(float a, float b) {
  // round-half-up fp32 -> bf16, packed pair (identical to verified baseline)
  return ((__float_as_uint(a) + 0x8000u) >> 16) | ((__float_as_uint(b) + 0x8000u) & 0xFFFF0000u);
}

// W -> fragment-major bf16: WbP[((kt*16 + T)*64 + lane)*8 + e] =
//   bf16(W[T*16 + (lane&15)][kt*32 + (lane>>4)*8 + e]);  row 255 zero pad.
__global__ __launch_bounds__(256) void prep_w(const float* __restrict__ W,
                                              const float* __restrict__ b,
                                              const float* __restrict__ beta,
                                              unsigned short* __restrict__ WbP,
                                              float* __restrict__ bp,
                                              float* __restrict__ betap) {
  int f = blockIdx.x * 256 + threadIdx.x;  // 0..65535 fragments
  int kt = f >> 10;
  int T = (f >> 6) & 15;
  int l = f & 63;
  int row = T * 16 + (l & 15);
  int k0 = kt * 32 + (l >> 4) * 8;
  uint4 o = make_uint4(0u, 0u, 0u, 0u);
  if (row < NINNER) {
    const float* src = W + (size_t)row * DIM + k0;
    o.x = cvt2bf(src[0], src[1]);
    o.y = cvt2bf(src[2], src[3]);
    o.z = cvt2bf(src[4], src[5]);
    o.w = cvt2bf(src[6], src[7]);
  }
  *(uint4*)(WbP + (size_t)f * 8) = o;
  if (f < NPAD) {
    bp[f] = (f < NINNER) ? b[f] : 0.f;
    betap[f] = (f < NINNER) ? beta[f] : 0.f;
  }
}

__global__ __launch_bounds__(256) void leaf_softmax(const float* __restrict__ leaf,
                                                    float* __restrict__ logQT,
                                                    float* __restrict__ Q) {
  int l = blockIdx.x, t = threadIdx.x;
  const float* row = leaf + (size_t)l * NCLS;
  __shared__ float red[256];
  float mx = -3.4e38f;
  for (int j = t; j < NCLS; j += 256) mx = fmaxf(mx, row[j]);
  red[t] = mx; __syncthreads();
  for (int s = 128; s; s >>= 1) { if (t < s) red[t] = fmaxf(red[t], red[t + s]); __syncthreads(); }
  mx = red[0]; __syncthreads();
  float sm = 0.f;
  for (int j = t; j < NCLS; j += 256) sm += __expf(row[j] - mx);
  red[t] = sm; __syncthreads();
  for (int s = 128; s; s >>= 1) { if (t < s) red[t] += red[t + s]; __syncthreads(); }
  float lse = mx + __logf(red[0]);
  for (int j = t; j < NCLS; j += 256) {
    float lg = row[j] - lse;
    logQT[(size_t)j * NPAD + l] = lg;      // transposed: [class][leaf]
    Q[(size_t)l * NCLS + j] = __expf(lg);
  }
}

__global__ __launch_bounds__(256) void find_targets(const float* __restrict__ y,
                                                    int* __restrict__ tgt) {
  int wv = threadIdx.x >> 6, lane = threadIdx.x & 63;
  int r = blockIdx.x * 4 + wv;
  const float4* yr = (const float4*)(y + (size_t)r * NCLS);
  int found = 0x7fffffff;
#pragma unroll
  for (int i = 0; i < 4; ++i) {
    int j4 = i * 64 + lane;
    if (j4 < 250) {
      float4 v = yr[j4];
      if (v.x > 0.5f) found = min(found, 4 * j4 + 0);
      if (v.y > 0.5f) found = min(found, 4 * j4 + 1);
      if (v.z > 0.5f) found = min(found, 4 * j4 + 2);
      if (v.w > 0.5f) found = min(found, 4 * j4 + 3);
    }
  }
  for (int off = 32; off; off >>= 1) found = min(found, __shfl_down(found, off));
  if (lane == 0) tgt[r] = found;
}

// ---- direct-to-register GEMM pipeline stages (named sets, rule #20) ----
// Per k-step (32 k): A = 2 rows-of-16 x 32 B/lane (4x float4), B = 2 frags (short8).
#define DECLF(S) float4 S##a00, S##a01, S##a10, S##a11; short8 S##b0, S##b1;

#define LOADK(S, kt) do {                                                    \
  const float* _a0 = arow0 + (size_t)(kt) * 32;                              \
  const float* _a1 = arow1 + (size_t)(kt) * 32;                              \
  S##a00 = *(const float4*)_a0;  S##a01 = *(const float4*)(_a0 + 4);         \
  S##a10 = *(const float4*)_a1;  S##a11 = *(const float4*)(_a1 + 4);         \
  const unsigned short* _b = bptr + (size_t)(kt) * 8192;                     \
  S##b0 = *(const short8*)(_b);  S##b1 = *(const short8*)(_b + 512);         \
} while (0)

#define COMPUTE(S, AC) do {                                                  \
  short8 _afr0, _afr1;                                                       \
  { union { uint4 u; short8 s; } cv;                                         \
    cv.u.x = cvt2bf(S##a00.x, S##a00.y); cv.u.y = cvt2bf(S##a00.z, S##a00.w);\
    cv.u.z = cvt2bf(S##a01.x, S##a01.y); cv.u.w = cvt2bf(S##a01.z, S##a01.w);\
    _afr0 = cv.s; }                                                          \
  { union { uint4 u; short8 s; } cv;                                         \
    cv.u.x = cvt2bf(S##a10.x, S##a10.y); cv.u.y = cvt2bf(S##a10.z, S##a10.w);\
    cv.u.z = cvt2bf(S##a11.x, S##a11.y); cv.u.w = cvt2bf(S##a11.z, S##a11.w);\
    _afr1 = cv.s; }                                                          \
  AC[0][0] = __builtin_amdgcn_mfma_f32_16x16x32_bf16(_afr0, S##b0, AC[0][0], 0, 0, 0); \
  AC[1][0] = __builtin_amdgcn_mfma_f32_16x16x32_bf16(_afr1, S##b0, AC[1][0], 0, 0, 0); \
  AC[0][1] = __builtin_amdgcn_mfma_f32_16x16x32_bf16(_afr0, S##b1, AC[0][1], 0, 0, 0); \
  AC[1][1] = __builtin_amdgcn_mfma_f32_16x16x32_bf16(_afr1, S##b1, AC[1][1], 0, 0, 0); \
} while (0)

// Fused GEMM + sigmoid + tree walk. 512 blocks x 512 threads (8 waves),
// 2 blocks/CU = 16 waves/CU. Wave tile 32x32 (cols wave*32..+32); waves fully
// independent until the epilogue. Accumulator halves (k<1024 / k>=1024) keep
// the original P0+P1 summation order bit-exact.
__global__ __launch_bounds__(512, 4) void gemm_tree(
    const float* __restrict__ x, const unsigned short* __restrict__ WbP,
    const float* __restrict__ bp, const float* __restrict__ betap,
    const float* __restrict__ logQT, const int* __restrict__ tgt,
    float* __restrict__ acc, int* __restrict__ best) {
  __shared__ __align__(16) float Ps[32 * 256];  // epilogue P tile (32 KB)
  __shared__ float s0s[127], s1s[127], sdot;

  int tid = threadIdx.x;
  int lane = tid & 63, wave = tid >> 6;  // wave 0..7
  int frow = lane & 15, fq = lane >> 4;
  int m_base = blockIdx.x * BM;

  if (tid < 127) { s0s[tid] = 0.f; s1s[tid] = 0.f; }
  if (tid == 255) sdot = 0.f;

  // A: lane reads rows (m_base+frow) and (+16), 32 B at k = kt*32 + fq*8 floats.
  const float* arow0 = x + (size_t)(m_base + frow) * DIM + fq * 8;
  const float* arow1 = arow0 + (size_t)16 * DIM;
  // B: wave's n-tiles T = wave*2 + nt (cols wave*32..+32), fragment-major.
  const unsigned short* bptr = WbP + ((size_t)wave * 2 * 64 + lane) * 8;

  f32x4 accA[2][2] = {}, accB[2][2] = {};

  DECLF(s0_) DECLF(s1_)
  LOADK(s0_, 0);

  for (int kt = 0; kt < 32; kt += 2) {  // k < 1024 half -> accA
    LOADK(s1_, kt + 1);
    COMPUTE(s0_, accA);
    LOADK(s0_, kt + 2);  // kt=30 loads step 32 (first of next half) -- valid
    COMPUTE(s1_, accA);
  }
  for (int kt = 32; kt < 64; kt += 2) {  // k >= 1024 half -> accB
    LOADK(s1_, kt + 1);
    COMPUTE(s0_, accB);
    if (kt < 62) LOADK(s0_, kt + 2);
    COMPUTE(s1_, accB);
  }

  __syncthreads();  // only barrier before the epilogue

  // ---- fused epilogue: accumulators -> LDS P tile ----
#pragma unroll
  for (int mt = 0; mt < 2; ++mt)
#pragma unroll
    for (int nt = 0; nt < 2; ++nt)
#pragma unroll
      for (int rg = 0; rg < 4; ++rg)
        Ps[(mt * 16 + fq * 4 + rg) * 256 + wave * 32 + nt * 16 + frow] =
            accA[mt][nt][rg] + accB[mt][nt][rg];  // == (P0 + P1), same order as before
  __syncthreads();

  // sigmoid in place: thread owns column (tid&255), half the rows
  {
    int col = tid & 255;
    int r0 = (tid >> 8) * 16;
    float bc2 = bp[col], bec = betap[col];
#pragma unroll 4
    for (int i = r0; i < r0 + 16; ++i) {
      float v = Ps[i * 256 + col];
      Ps[i * 256 + col] = 1.f / (1.f + __expf(-bec * (v + bc2)));
    }
  }
  __syncthreads();

  // tree walk: wave handles rows wave*4 .. +4; node sums accumulated in regs
  float wdot = 0.f;
  float s0r[7] = {}, s1r[7] = {};
  for (int it = 0; it < 4; ++it) {
    int rl = wave * 4 + it;
    int r = m_base + rl;
    const float* wsp = Ps + rl * 256;
    int tg = tgt[r];
    float pp = 1.f;  // path product into current depth
#pragma unroll
    for (int d = 1; d <= 6; ++d) {
      int idx = (1 << (d - 1)) - 1 + (lane >> (7 - d));
      float p = wsp[idx];
      s0r[d - 1] += pp;       // only first covering lane's value is used later
      s1r[d - 1] += p * pp;
      pp *= ((lane >> (6 - d)) & 1) ? p : (1.f - p);
    }
    float p7 = wsp[63 + lane];
    s0r[6] += pp;
    s1r[6] += p7 * pp;
    float pL = pp * (1.f - p7), pR = pp * p7;
    float p8a = wsp[127 + 2 * lane], p8b = wsp[128 + 2 * lane];
    float lf0 = pL * (1.f - p8a), lf1 = pL * p8a;
    float lf2 = pR * (1.f - p8b), lf3 = pR * p8b;
    float4 lq = *(const float4*)(logQT + (size_t)tg * NPAD + lane * 4);
    wdot += lf0 * lq.x + lf1 * lq.y + lf2 * lq.z + lf3 * lq.w;
    float bv = lf0; int bi = 4 * lane;
    if (lf1 > bv) { bv = lf1; bi = 4 * lane + 1; }
    if (lf2 > bv) { bv = lf2; bi = 4 * lane + 2; }
    if (lf3 > bv) { bv = lf3; bi = 4 * lane + 3; }
    for (int off = 32; off; off >>= 1) {
      float ov = __shfl_down(bv, off);
      int oi = __shfl_down(bi, off);
      if (ov > bv || (ov == bv && oi < bi)) { bv = ov; bi = oi; }  // first-max tie-break
    }
    if (lane == 0) best[r] = bi;
  }
  // fold per-wave node sums into block LDS arrays
#pragma unroll
  for (int d = 1; d <= 6; ++d) {
    int idx = (1 << (d - 1)) - 1 + (lane >> (7 - d));
    if ((lane & ((1 << (7 - d)) - 1)) == 0) {
      atomicAdd(&s0s[idx], s0r[d - 1]);
      atomicAdd(&s1s[idx], s1r[d - 1]);
    }
  }
  atomicAdd(&s0s[63 + lane], s0r[6]);
  atomicAdd(&s1s[63 + lane], s1r[6]);
  for (int off = 32; off; off >>= 1) wdot += __shfl_down(wdot, off);
  if (lane == 0) atomicAdd(&sdot, wdot);
  __syncthreads();
  if (tid < 127) {
    atomicAdd(&acc[tid], s0s[tid]);
    atomicAdd(&acc[127 + tid], s1s[tid]);
  }
  if (tid == 255) atomicAdd(&acc[254], sdot);
}

__global__ __launch_bounds__(128) void finalize_loss(const float* __restrict__ acc,
                                                     float* __restrict__ out) {
  __shared__ float red[128];
  int t = threadIdx.x;
  float c = 0.f;
  if (t < 127) {
    float denom = acc[t];
    if (denom == 0.f) denom = 1e-6f;
    float alpha = acc[127 + t] / denom;
    alpha = fminf(fmaxf(alpha, 1e-6f), 1.f - 1e-6f);
    int d = 31 - __clz(t + 1) + 1;  // depth: idx 0 -> 1, idx 1..2 -> 2, ...
    float lm = 0.1f * exp2f(-(float)d);
    c = -lm * 0.5f * (logf(alpha) + log1pf(-alpha));
  }
  red[t] = c;
  __syncthreads();
  for (int s = 64; s; s >>= 1) { if (t < s) red[t] += red[t + s]; __syncthreads(); }
  if (t == 0) out[0] = -(acc[254] / 16384.f) + red[0];
}

__global__ __launch_bounds__(256) void gather_rows(const float* __restrict__ Q,
                                                   const int* __restrict__ best,
                                                   float* __restrict__ out) {
  int wv = threadIdx.x >> 6, lane = threadIdx.x & 63;
  int r = blockIdx.x * 4 + wv;
  const float* src = Q + (size_t)best[r] * NCLS;
  float* dst = out + 1 + (size_t)r * NCLS;  // rows start at global index 1+1000r
  if (lane < 3) dst[lane] = src[lane];
  if (lane == 0) dst[999] = src[999];
#pragma unroll
  for (int i = 0; i < 4; ++i) {
    int q = i * 64 + lane;
    if (q < 249) {
      int o = 3 + 4 * q;  // 16B-aligned in dst
      float4 v = make_float4(src[o], src[o + 1], src[o + 2], src[o + 3]);
      *(float4*)(dst + o) = v;
    }
  }
}

extern "C" void kernel_launch(void* const* d_in, const int* in_sizes, int n_in,
                              void* d_out, int out_size, void* d_ws, size_t ws_size,
                              hipStream_t stream) {
  const float* x = (const float*)d_in[0];
  const float* y = (const float*)d_in[1];
  const float* W = (const float*)d_in[2];
  const float* b = (const float*)d_in[3];
  const float* beta = (const float*)d_in[4];
  const float* leaf = (const float*)d_in[5];
  float* out = (float*)d_out;
  char* ws = (char*)d_ws;

  unsigned short* WbP = (unsigned short*)(ws + 0);       // 1048576 (fragment-major)
  float* bp    = (float*)(ws + 1048576);                 // 1024
  float* betap = (float*)(ws + 1049600);                 // 1024
  float* accb  = (float*)(ws + 1050624);                 // 1024 (255 used)
  int* tgt     = (int*)(ws + 1051648);                   // 65536
  int* best    = (int*)(ws + 1117184);                   // 65536
  float* logQT = (float*)(ws + 1182720);                 // 1000*256*4 = 1024000
  float* Q     = (float*)(ws + 2206720);                 // 1024000

  prep_w<<<256, 256, 0, stream>>>(W, b, beta, WbP, bp, betap);
  leaf_softmax<<<256, 256, 0, stream>>>(leaf, logQT, Q);
  find_targets<<<4096, 256, 0, stream>>>(y, tgt);
  hipMemsetAsync(accb, 0, 256 * sizeof(float), stream);
  gemm_tree<<<512, 512, 0, stream>>>(x, WbP, bp, betap, logQT, tgt, accb, best);
  finalize_loss<<<1, 128, 0, stream>>>(accb, out);
  gather_rows<<<4096, 256, 0, stream>>>(Q, best, out);
}

// Round 5
// 342.403 us; speedup vs baseline: 1.1284x; 1.1284x over previous
//
#include <hip/hip_runtime.h>

// SoftDecisionTree fused pipeline for MI355X (gfx950).
// Inputs: x[16384,2048] f32, y[16384,1000] f32 one-hot, W[255,2048] f32,
//         b[255] f32, beta[255] f32, leaf_params[256,1000] f32
// Output: [loss(1) | output(16384*1000)] f32
//
// v5: contiguous-access GEMM via fragment-major re-tiled inputs.
//  - v1-v4 all pinned at ~25 GB/s/CU vector-memory throughput: every A access
//    read 16-32 rows at stride 8192 B per instruction (power-of-two pitch ->
//    channel/bank hotspotting; effective latency ~9000 cyc by Little's law).
//  - prep_x re-tiles x into fragment-major bf16 xP (same values as cvt2bf at
//    use -> bit-identical), so gemm A-loads are linear per-block streams
//    (1 KB contiguous per instruction, shared by all 8 waves via L1).
//  - gemm: no cvt in loop, 16 VGPR/stage, named 4-deep pipeline pinned with
//    sched_barrier(0); no barriers in the K loop; v4's verified epilogue.

typedef __attribute__((ext_vector_type(8))) short short8;
typedef __attribute__((ext_vector_type(4))) float f32x4;

#define DIM 2048
#define NCLS 1000
#define NINNER 255
#define NPAD 256
#define BM 32        // rows per block (8 waves: wave tile 32x32 covers N=256)

__device__ __forceinline__ unsigned cvt2bf(float a, float b) {
  // round-half-up fp32 -> bf16, packed pair (identical to verified baseline)
  return ((__float_as_uint(a) + 0x8000u) >> 16) | ((__float_as_uint(b) + 0x8000u) & 0xFFFF0000u);
}

// W -> fragment-major bf16: WbP[((kt*16 + T)*64 + lane)*8 + e] =
//   bf16(W[T*16 + (lane&15)][kt*32 + (lane>>4)*8 + e]);  row 255 zero pad.
__global__ __launch_bounds__(256) void prep_w(const float* __restrict__ W,
                                              const float* __restrict__ b,
                                              const float* __restrict__ beta,
                                              unsigned short* __restrict__ WbP,
                                              float* __restrict__ bp,
                                              float* __restrict__ betap) {
  int f = blockIdx.x * 256 + threadIdx.x;  // 0..65535 fragments
  int kt = f >> 10;
  int T = (f >> 6) & 15;
  int l = f & 63;
  int row = T * 16 + (l & 15);
  int k0 = kt * 32 + (l >> 4) * 8;
  uint4 o = make_uint4(0u, 0u, 0u, 0u);
  if (row < NINNER) {
    const float* src = W + (size_t)row * DIM + k0;
    o.x = cvt2bf(src[0], src[1]);
    o.y = cvt2bf(src[2], src[3]);
    o.z = cvt2bf(src[4], src[5]);
    o.w = cvt2bf(src[6], src[7]);
  }
  *(uint4*)(WbP + (size_t)f * 8) = o;
  if (f < NPAD) {
    bp[f] = (f < NINNER) ? b[f] : 0.f;
    betap[f] = (f < NINNER) ? beta[f] : 0.f;
  }
}

// x -> fragment-major bf16: xP[((bm*64 + kt)*2 + mt)*512 + lane*8 + e] =
//   bf16(x[bm*32 + mt*16 + (lane&15)][kt*32 + (lane>>4)*8 + e]).
// Block (bm, kg) handles 32 rows x 256 k: coalesced reads -> LDS transpose ->
// one contiguous 16 KB write. Both global sides per-instruction contiguous.
__global__ __launch_bounds__(256) void prep_x(const float* __restrict__ x,
                                              unsigned short* __restrict__ xP) {
  __shared__ __align__(16) unsigned short ls[8192];  // 16 KB
  int bm = blockIdx.x >> 3, kg = blockIdx.x & 7;
  int t = threadIdx.x;
  int r = t >> 3, s = t & 3 | (t & 7);  // placeholder avoided below
  s = t & 7;
  const float* src = x + (size_t)(bm * 32 + r) * DIM + kg * 256 + s * 32;
  unsigned short* dstl = ls + (((s * 2 + (r >> 4)) * 64 + (r & 15)) * 8);
#pragma unroll
  for (int fq = 0; fq < 4; ++fq) {
    float4 va = *(const float4*)(src + fq * 8);
    float4 vb = *(const float4*)(src + fq * 8 + 4);
    uint4 o;
    o.x = cvt2bf(va.x, va.y); o.y = cvt2bf(va.z, va.w);
    o.z = cvt2bf(vb.x, vb.y); o.w = cvt2bf(vb.z, vb.w);
    *(uint4*)(dstl + fq * 128) = o;  // fq advances 16 lanes = 128 shorts
  }
  __syncthreads();
  const uint4* lsv = (const uint4*)ls;
  uint4* outv = (uint4*)(xP + ((size_t)bm * 64 + kg * 8) * 1024);
#pragma unroll
  for (int i = 0; i < 4; ++i) outv[t * 4 + i] = lsv[t * 4 + i];
}

__global__ __launch_bounds__(256) void leaf_softmax(const float* __restrict__ leaf,
                                                    float* __restrict__ logQT,
                                                    float* __restrict__ Q) {
  int l = blockIdx.x, t = threadIdx.x;
  const float* row = leaf + (size_t)l * NCLS;
  __shared__ float red[256];
  float mx = -3.4e38f;
  for (int j = t; j < NCLS; j += 256) mx = fmaxf(mx, row[j]);
  red[t] = mx; __syncthreads();
  for (int s = 128; s; s >>= 1) { if (t < s) red[t] = fmaxf(red[t], red[t + s]); __syncthreads(); }
  mx = red[0]; __syncthreads();
  float sm = 0.f;
  for (int j = t; j < NCLS; j += 256) sm += __expf(row[j] - mx);
  red[t] = sm; __syncthreads();
  for (int s = 128; s; s >>= 1) { if (t < s) red[t] += red[t + s]; __syncthreads(); }
  float lse = mx + __logf(red[0]);
  for (int j = t; j < NCLS; j += 256) {
    float lg = row[j] - lse;
    logQT[(size_t)j * NPAD + l] = lg;      // transposed: [class][leaf]
    Q[(size_t)l * NCLS + j] = __expf(lg);
  }
}

__global__ __launch_bounds__(256) void find_targets(const float* __restrict__ y,
                                                    int* __restrict__ tgt) {
  int wv = threadIdx.x >> 6, lane = threadIdx.x & 63;
  int r = blockIdx.x * 4 + wv;
  const float4* yr = (const float4*)(y + (size_t)r * NCLS);
  int found = 0x7fffffff;
#pragma unroll
  for (int i = 0; i < 4; ++i) {
    int j4 = i * 64 + lane;
    if (j4 < 250) {
      float4 v = yr[j4];
      if (v.x > 0.5f) found = min(found, 4 * j4 + 0);
      if (v.y > 0.5f) found = min(found, 4 * j4 + 1);
      if (v.z > 0.5f) found = min(found, 4 * j4 + 2);
      if (v.w > 0.5f) found = min(found, 4 * j4 + 3);
    }
  }
  for (int off = 32; off; off >>= 1) found = min(found, __shfl_down(found, off));
  if (lane == 0) tgt[r] = found;
}

// ---- direct-to-register GEMM pipeline stages (named sets, rule #20) ----
// Per k-step: A = 2 bf16 frags from xP (contiguous), B = 2 frags from WbP.
#define DECLF(S) short8 S##a0, S##a1, S##b0, S##b1;

#define LOADK(S, kt) do {                                                    \
  S##a0 = *(const short8*)(aptr + (size_t)(kt) * 1024);                      \
  S##a1 = *(const short8*)(aptr + (size_t)(kt) * 1024 + 512);                \
  S##b0 = *(const short8*)(bptr + (size_t)(kt) * 8192);                      \
  S##b1 = *(const short8*)(bptr + (size_t)(kt) * 8192 + 512);                \
  __builtin_amdgcn_sched_barrier(0);  /* pin: loads stay issued here */      \
} while (0)

#define COMPUTE(S, AC) do {                                                  \
  AC[0][0] = __builtin_amdgcn_mfma_f32_16x16x32_bf16(S##a0, S##b0, AC[0][0], 0, 0, 0); \
  AC[1][0] = __builtin_amdgcn_mfma_f32_16x16x32_bf16(S##a1, S##b0, AC[1][0], 0, 0, 0); \
  AC[0][1] = __builtin_amdgcn_mfma_f32_16x16x32_bf16(S##a0, S##b1, AC[0][1], 0, 0, 0); \
  AC[1][1] = __builtin_amdgcn_mfma_f32_16x16x32_bf16(S##a1, S##b1, AC[1][1], 0, 0, 0); \
} while (0)

// Fused GEMM + sigmoid + tree walk. 512 blocks x 512 threads (8 waves),
// launch_bounds(512,4) -> 2 blocks/CU = 16 waves/CU. Wave tile 32x32.
// Accumulator halves (k<1024 / k>=1024) keep the P0+P1 summation bit-exact.
__global__ __launch_bounds__(512, 4) void gemm_tree(
    const unsigned short* __restrict__ xP, const unsigned short* __restrict__ WbP,
    const float* __restrict__ bp, const float* __restrict__ betap,
    const float* __restrict__ logQT, const int* __restrict__ tgt,
    float* __restrict__ acc, int* __restrict__ best) {
  __shared__ __align__(16) float Ps[32 * 256];  // epilogue P tile (32 KB)
  __shared__ float s0s[127], s1s[127], sdot;

  int tid = threadIdx.x;
  int lane = tid & 63, wave = tid >> 6;  // wave 0..7
  int frow = lane & 15, fq = lane >> 4;
  int m_base = blockIdx.x * BM;

  if (tid < 127) { s0s[tid] = 0.f; s1s[tid] = 0.f; }
  if (tid == 255) sdot = 0.f;

  // A: block-private contiguous 128 KB region; same addrs for all 8 waves (L1).
  const unsigned short* aptr = xP + (size_t)blockIdx.x * 65536 + lane * 8;
  // B: wave's n-tiles T = wave*2 + nt (cols wave*32..+32), fragment-major.
  const unsigned short* bptr = WbP + (size_t)wave * 1024 + lane * 8;

  f32x4 accA[2][2] = {}, accB[2][2] = {};

  DECLF(s0_) DECLF(s1_) DECLF(s2_) DECLF(s3_)
  LOADK(s0_, 0); LOADK(s1_, 1); LOADK(s2_, 2);

  for (int kt = 0; kt < 32; kt += 4) {  // k < 1024 half -> accA
    LOADK(s3_, kt + 3);
    COMPUTE(s0_, accA); LOADK(s0_, kt + 4);
    COMPUTE(s1_, accA); LOADK(s1_, kt + 5);
    COMPUTE(s2_, accA); LOADK(s2_, kt + 6);
    COMPUTE(s3_, accA);
  }
  for (int kt = 32; kt < 56; kt += 4) {  // k >= 1024 half -> accB
    LOADK(s3_, kt + 3);
    COMPUTE(s0_, accB); LOADK(s0_, kt + 4);
    COMPUTE(s1_, accB); LOADK(s1_, kt + 5);
    COMPUTE(s2_, accB); LOADK(s2_, kt + 6);
    COMPUTE(s3_, accB);
  }
  // tail: kt=56 iteration without further prefetch (s0=60,s1=61,s2=62 loaded)
  LOADK(s3_, 59);
  COMPUTE(s0_, accB); COMPUTE(s1_, accB); COMPUTE(s2_, accB); COMPUTE(s3_, accB);
  LOADK(s3_, 63);
  // reuse s0..s2 already holding 60..62
  COMPUTE(s0_, accB); COMPUTE(s1_, accB); COMPUTE(s2_, accB); COMPUTE(s3_, accB);

  __syncthreads();  // only barrier before the epilogue

  // ---- fused epilogue: accumulators -> LDS P tile ----
#pragma unroll
  for (int mt = 0; mt < 2; ++mt)
#pragma unroll
    for (int nt = 0; nt < 2; ++nt)
#pragma unroll
      for (int rg = 0; rg < 4; ++rg)
        Ps[(mt * 16 + fq * 4 + rg) * 256 + wave * 32 + nt * 16 + frow] =
            accA[mt][nt][rg] + accB[mt][nt][rg];  // == (P0 + P1), same order as before
  __syncthreads();

  // sigmoid in place: thread owns column (tid&255), half the rows
  {
    int col = tid & 255;
    int r0 = (tid >> 8) * 16;
    float bc2 = bp[col], bec = betap[col];
#pragma unroll 4
    for (int i = r0; i < r0 + 16; ++i) {
      float v = Ps[i * 256 + col];
      Ps[i * 256 + col] = 1.f / (1.f + __expf(-bec * (v + bc2)));
    }
  }
  __syncthreads();

  // tree walk: wave handles rows wave*4 .. +4; node sums accumulated in regs
  float wdot = 0.f;
  float s0r[7] = {}, s1r[7] = {};
  for (int it = 0; it < 4; ++it) {
    int rl = wave * 4 + it;
    int r = m_base + rl;
    const float* wsp = Ps + rl * 256;
    int tg = tgt[r];
    float pp = 1.f;  // path product into current depth
#pragma unroll
    for (int d = 1; d <= 6; ++d) {
      int idx = (1 << (d - 1)) - 1 + (lane >> (7 - d));
      float p = wsp[idx];
      s0r[d - 1] += pp;       // only first covering lane's value is used later
      s1r[d - 1] += p * pp;
      pp *= ((lane >> (6 - d)) & 1) ? p : (1.f - p);
    }
    float p7 = wsp[63 + lane];
    s0r[6] += pp;
    s1r[6] += p7 * pp;
    float pL = pp * (1.f - p7), pR = pp * p7;
    float p8a = wsp[127 + 2 * lane], p8b = wsp[128 + 2 * lane];
    float lf0 = pL * (1.f - p8a), lf1 = pL * p8a;
    float lf2 = pR * (1.f - p8b), lf3 = pR * p8b;
    float4 lq = *(const float4*)(logQT + (size_t)tg * NPAD + lane * 4);
    wdot += lf0 * lq.x + lf1 * lq.y + lf2 * lq.z + lf3 * lq.w;
    float bv = lf0; int bi = 4 * lane;
    if (lf1 > bv) { bv = lf1; bi = 4 * lane + 1; }
    if (lf2 > bv) { bv = lf2; bi = 4 * lane + 2; }
    if (lf3 > bv) { bv = lf3; bi = 4 * lane + 3; }
    for (int off = 32; off; off >>= 1) {
      float ov = __shfl_down(bv, off);
      int oi = __shfl_down(bi, off);
      if (ov > bv || (ov == bv && oi < bi)) { bv = ov; bi = oi; }  // first-max tie-break
    }
    if (lane == 0) best[r] = bi;
  }
  // fold per-wave node sums into block LDS arrays
#pragma unroll
  for (int d = 1; d <= 6; ++d) {
    int idx = (1 << (d - 1)) - 1 + (lane >> (7 - d));
    if ((lane & ((1 << (7 - d)) - 1)) == 0) {
      atomicAdd(&s0s[idx], s0r[d - 1]);
      atomicAdd(&s1s[idx], s1r[d - 1]);
    }
  }
  atomicAdd(&s0s[63 + lane], s0r[6]);
  atomicAdd(&s1s[63 + lane], s1r[6]);
  for (int off = 32; off; off >>= 1) wdot += __shfl_down(wdot, off);
  if (lane == 0) atomicAdd(&sdot, wdot);
  __syncthreads();
  if (tid < 127) {
    atomicAdd(&acc[tid], s0s[tid]);
    atomicAdd(&acc[127 + tid], s1s[tid]);
  }
  if (tid == 255) atomicAdd(&acc[254], sdot);
}

__global__ __launch_bounds__(128) void finalize_loss(const float* __restrict__ acc,
                                                     float* __restrict__ out) {
  __shared__ float red[128];
  int t = threadIdx.x;
  float c = 0.f;
  if (t < 127) {
    float denom = acc[t];
    if (denom == 0.f) denom = 1e-6f;
    float alpha = acc[127 + t] / denom;
    alpha = fminf(fmaxf(alpha, 1e-6f), 1.f - 1e-6f);
    int d = 31 - __clz(t + 1) + 1;  // depth: idx 0 -> 1, idx 1..2 -> 2, ...
    float lm = 0.1f * exp2f(-(float)d);
    c = -lm * 0.5f * (logf(alpha) + log1pf(-alpha));
  }
  red[t] = c;
  __syncthreads();
  for (int s = 64; s; s >>= 1) { if (t < s) red[t] += red[t + s]; __syncthreads(); }
  if (t == 0) out[0] = -(acc[254] / 16384.f) + red[0];
}

__global__ __launch_bounds__(256) void gather_rows(const float* __restrict__ Q,
                                                   const int* __restrict__ best,
                                                   float* __restrict__ out) {
  int wv = threadIdx.x >> 6, lane = threadIdx.x & 63;
  int r = blockIdx.x * 4 + wv;
  const float* src = Q + (size_t)best[r] * NCLS;
  float* dst = out + 1 + (size_t)r * NCLS;  // rows start at global index 1+1000r
  if (lane < 3) dst[lane] = src[lane];
  if (lane == 0) dst[999] = src[999];
#pragma unroll
  for (int i = 0; i < 4; ++i) {
    int q = i * 64 + lane;
    if (q < 249) {
      int o = 3 + 4 * q;  // 16B-aligned in dst
      float4 v = make_float4(src[o], src[o + 1], src[o + 2], src[o + 3]);
      *(float4*)(dst + o) = v;
    }
  }
}

extern "C" void kernel_launch(void* const* d_in, const int* in_sizes, int n_in,
                              void* d_out, int out_size, void* d_ws, size_t ws_size,
                              hipStream_t stream) {
  const float* x = (const float*)d_in[0];
  const float* y = (const float*)d_in[1];
  const float* W = (const float*)d_in[2];
  const float* b = (const float*)d_in[3];
  const float* beta = (const float*)d_in[4];
  const float* leaf = (const float*)d_in[5];
  float* out = (float*)d_out;
  char* ws = (char*)d_ws;

  unsigned short* WbP = (unsigned short*)(ws + 0);       // 1048576 (fragment-major)
  float* bp    = (float*)(ws + 1048576);                 // 1024
  float* betap = (float*)(ws + 1049600);                 // 1024
  float* accb  = (float*)(ws + 1050624);                 // 1024 (255 used)
  int* tgt     = (int*)(ws + 1051648);                   // 65536
  int* best    = (int*)(ws + 1117184);                   // 65536
  float* logQT = (float*)(ws + 1182720);                 // 1000*256*4 = 1024000
  float* Q     = (float*)(ws + 2206720);                 // 1024000
  unsigned short* xP = (unsigned short*)(ws + 4194304);  // 16384*2048*2 = 64 MB

  prep_w<<<256, 256, 0, stream>>>(W, b, beta, WbP, bp, betap);
  prep_x<<<4096, 256, 0, stream>>>(x, xP);
  leaf_softmax<<<256, 256, 0, stream>>>(leaf, logQT, Q);
  find_targets<<<4096, 256, 0, stream>>>(y, tgt);
  hipMemsetAsync(accb, 0, 256 * sizeof(float), stream);
  gemm_tree<<<512, 512, 0, stream>>>(xP, WbP, bp, betap, logQT, tgt, accb, best);
  finalize_loss<<<1, 128, 0, stream>>>(accb, out);
  gather_rows<<<4096, 256, 0, stream>>>(Q, best, out);
}

// Round 7
// 318.253 us; speedup vs baseline: 1.2141x; 1.0759x over previous
//
#include <hip/hip_runtime.h>

// SoftDecisionTree fused pipeline for MI355X (gfx950).
// Inputs: x[16384,2048] f32, y[16384,1000] f32 one-hot, W[255,2048] f32,
//         b[255] f32, beta[255] f32, leaf_params[256,1000] f32
// Output: [loss(1) | output(16384*1000)] f32
//
// v6 (resubmit -- round-6 bench died on container acquire, no kernel verdict):
// 3-launch pipeline.
//  1. prep_all (grid 8704x256, branch on blockIdx -- all branches independent):
//       [0,256)    leaf_softmax: logQT = log_softmax(leaf)^T, Q = exp
//       [256,512)  prep_w: W -> fragment-major bf16 WbP; pad b/beta; zero acc
//       [512,4608) prep_x: x -> fragment-major bf16 xP (contiguous GEMM A)
//       [4608,8704) find_targets: tgt = argmax_j y
//  2. gemm_tree (512 x 512): direct-to-register bf16 MFMA GEMM (contiguous
//     A from xP, B from L2-resident WbP, 4-deep named pipeline, no barriers
//     in the K loop) + fused sigmoid + tree walk + node sums + logQT dot +
//     argmax.  v5's tail bug FIXED: steps 60-62 were never computed (56-58
//     done twice); now every kt 0..63 is computed exactly once in order.
//  3. gather_loss (4097 x 256): rows = Q[best]; block 4096 computes loss.
//
// Numerics bit-identical to the verified r1-r4 kernels (absmax canary
// 0.04762268): same cvt2bf rounding, same per-element k-order, same
// accA (k<1024) + accB (k>=1024) summation split.

typedef __attribute__((ext_vector_type(8))) short short8;
typedef __attribute__((ext_vector_type(4))) float f32x4;

#define DIM 2048
#define NCLS 1000
#define NINNER 255
#define NPAD 256
#define BM 32        // rows per gemm block (8 waves: wave tile 32x32, N=256)

__device__ __forceinline__ unsigned cvt2bf(float a, float b) {
  // round-half-up fp32 -> bf16, packed pair (identical to verified baseline)
  return ((__float_as_uint(a) + 0x8000u) >> 16) | ((__float_as_uint(b) + 0x8000u) & 0xFFFF0000u);
}

// ---- prep_all: four independent prep stages in one launch ----
__global__ __launch_bounds__(256) void prep_all(
    const float* __restrict__ x, const float* __restrict__ y,
    const float* __restrict__ W, const float* __restrict__ b,
    const float* __restrict__ beta, const float* __restrict__ leaf,
    unsigned short* __restrict__ WbP, unsigned short* __restrict__ xP,
    float* __restrict__ bp, float* __restrict__ betap,
    float* __restrict__ logQT, float* __restrict__ Q,
    int* __restrict__ tgt, float* __restrict__ accb) {
  __shared__ __align__(16) unsigned short ls[8192];  // prep_x transpose (16 KB)
  __shared__ float red[256];                         // leaf_softmax reduction
  int bid = blockIdx.x;
  int t = threadIdx.x;

  if (bid < 256) {
    // ---- leaf_softmax: l = bid ----
    int l = bid;
    const float* row = leaf + (size_t)l * NCLS;
    float mx = -3.4e38f;
    for (int j = t; j < NCLS; j += 256) mx = fmaxf(mx, row[j]);
    red[t] = mx; __syncthreads();
    for (int s = 128; s; s >>= 1) { if (t < s) red[t] = fmaxf(red[t], red[t + s]); __syncthreads(); }
    mx = red[0]; __syncthreads();
    float sm = 0.f;
    for (int j = t; j < NCLS; j += 256) sm += __expf(row[j] - mx);
    red[t] = sm; __syncthreads();
    for (int s = 128; s; s >>= 1) { if (t < s) red[t] += red[t + s]; __syncthreads(); }
    float lse = mx + __logf(red[0]);
    for (int j = t; j < NCLS; j += 256) {
      float lg = row[j] - lse;
      logQT[(size_t)j * NPAD + l] = lg;      // transposed: [class][leaf]
      Q[(size_t)l * NCLS + j] = __expf(lg);
    }
  } else if (bid < 512) {
    // ---- prep_w: W -> fragment-major bf16 WbP[((kt*16+T)*64+lane)*8+e] ----
    int f = (bid - 256) * 256 + t;  // 0..65535 fragments
    int kt = f >> 10;
    int T = (f >> 6) & 15;
    int l = f & 63;
    int row = T * 16 + (l & 15);
    int k0 = kt * 32 + (l >> 4) * 8;
    uint4 o = make_uint4(0u, 0u, 0u, 0u);
    if (row < NINNER) {
      const float* src = W + (size_t)row * DIM + k0;
      o.x = cvt2bf(src[0], src[1]);
      o.y = cvt2bf(src[2], src[3]);
      o.z = cvt2bf(src[4], src[5]);
      o.w = cvt2bf(src[6], src[7]);
    }
    *(uint4*)(WbP + (size_t)f * 8) = o;
    if (f < NPAD) {
      bp[f] = (f < NINNER) ? b[f] : 0.f;
      betap[f] = (f < NINNER) ? beta[f] : 0.f;
      accb[f] = 0.f;  // replaces the hipMemsetAsync launch
    }
  } else if (bid < 4608) {
    // ---- prep_x: x -> fragment-major bf16
    // xP[((bm*64+kt)*2+mt)*512 + lane*8 + e] =
    //   bf16(x[bm*32 + mt*16 + (lane&15)][kt*32 + (lane>>4)*8 + e])
    int bx = bid - 512;
    int bm = bx >> 3, kg = bx & 7;
    int r = t >> 3, s = t & 7;
    const float* src = x + (size_t)(bm * 32 + r) * DIM + kg * 256 + s * 32;
    unsigned short* dstl = ls + (((s * 2 + (r >> 4)) * 64 + (r & 15)) * 8);
#pragma unroll
    for (int fq = 0; fq < 4; ++fq) {
      float4 va = *(const float4*)(src + fq * 8);
      float4 vb = *(const float4*)(src + fq * 8 + 4);
      uint4 o;
      o.x = cvt2bf(va.x, va.y); o.y = cvt2bf(va.z, va.w);
      o.z = cvt2bf(vb.x, vb.y); o.w = cvt2bf(vb.z, vb.w);
      *(uint4*)(dstl + fq * 128) = o;  // fq advances 16 lanes = 128 shorts
    }
    __syncthreads();
    const uint4* lsv = (const uint4*)ls;
    uint4* outv = (uint4*)(xP + ((size_t)bm * 64 + kg * 8) * 1024);
#pragma unroll
    for (int i = 0; i < 4; ++i) outv[t * 4 + i] = lsv[t * 4 + i];
  } else {
    // ---- find_targets: r = (bid-4608)*4 + wave ----
    int wv = t >> 6, lane = t & 63;
    int r = (bid - 4608) * 4 + wv;
    const float4* yr = (const float4*)(y + (size_t)r * NCLS);
    int found = 0x7fffffff;
#pragma unroll
    for (int i = 0; i < 4; ++i) {
      int j4 = i * 64 + lane;
      if (j4 < 250) {
        float4 v = yr[j4];
        if (v.x > 0.5f) found = min(found, 4 * j4 + 0);
        if (v.y > 0.5f) found = min(found, 4 * j4 + 1);
        if (v.z > 0.5f) found = min(found, 4 * j4 + 2);
        if (v.w > 0.5f) found = min(found, 4 * j4 + 3);
      }
    }
    for (int off = 32; off; off >>= 1) found = min(found, __shfl_down(found, off));
    if (lane == 0) tgt[r] = found;
  }
}

// ---- direct-to-register GEMM pipeline stages (named sets, rule #20) ----
// Per k-step: A = 2 bf16 frags from xP (contiguous), B = 2 frags from WbP.
#define DECLF(S) short8 S##a0, S##a1, S##b0, S##b1;

#define LOADK(S, kt) do {                                                    \
  S##a0 = *(const short8*)(aptr + (size_t)(kt) * 1024);                      \
  S##a1 = *(const short8*)(aptr + (size_t)(kt) * 1024 + 512);                \
  S##b0 = *(const short8*)(bptr + (size_t)(kt) * 8192);                      \
  S##b1 = *(const short8*)(bptr + (size_t)(kt) * 8192 + 512);                \
  __builtin_amdgcn_sched_barrier(0);  /* pin: loads stay issued here */      \
} while (0)

#define COMPUTE(S, AC) do {                                                  \
  AC[0][0] = __builtin_amdgcn_mfma_f32_16x16x32_bf16(S##a0, S##b0, AC[0][0], 0, 0, 0); \
  AC[1][0] = __builtin_amdgcn_mfma_f32_16x16x32_bf16(S##a1, S##b0, AC[1][0], 0, 0, 0); \
  AC[0][1] = __builtin_amdgcn_mfma_f32_16x16x32_bf16(S##a0, S##b1, AC[0][1], 0, 0, 0); \
  AC[1][1] = __builtin_amdgcn_mfma_f32_16x16x32_bf16(S##a1, S##b1, AC[1][1], 0, 0, 0); \
} while (0)

// Fused GEMM + sigmoid + tree walk. 512 blocks x 512 threads (8 waves),
// launch_bounds(512,4) -> 2 blocks/CU = 16 waves/CU. Wave tile 32x32.
// Accumulator halves (k<1024 / k>=1024) keep the P0+P1 summation bit-exact.
__global__ __launch_bounds__(512, 4) void gemm_tree(
    const unsigned short* __restrict__ xP, const unsigned short* __restrict__ WbP,
    const float* __restrict__ bp, const float* __restrict__ betap,
    const float* __restrict__ logQT, const int* __restrict__ tgt,
    float* __restrict__ acc, int* __restrict__ best) {
  __shared__ __align__(16) float Ps[32 * 256];  // epilogue P tile (32 KB)
  __shared__ float s0s[127], s1s[127], sdot;

  int tid = threadIdx.x;
  int lane = tid & 63, wave = tid >> 6;  // wave 0..7
  int frow = lane & 15, fq = lane >> 4;
  int m_base = blockIdx.x * BM;

  if (tid < 127) { s0s[tid] = 0.f; s1s[tid] = 0.f; }
  if (tid == 255) sdot = 0.f;

  // A: block-private contiguous 128 KB region; same addrs for all 8 waves (L1).
  const unsigned short* aptr = xP + (size_t)blockIdx.x * 65536 + lane * 8;
  // B: wave's n-tiles T = wave*2 + nt (cols wave*32..+32), fragment-major.
  const unsigned short* bptr = WbP + (size_t)wave * 1024 + lane * 8;

  f32x4 accA[2][2] = {}, accB[2][2] = {};

  DECLF(s0_) DECLF(s1_) DECLF(s2_) DECLF(s3_)
  LOADK(s0_, 0); LOADK(s1_, 1); LOADK(s2_, 2);

  for (int kt = 0; kt < 32; kt += 4) {  // k < 1024 half -> accA
    LOADK(s3_, kt + 3);
    COMPUTE(s0_, accA); LOADK(s0_, kt + 4);
    COMPUTE(s1_, accA); LOADK(s1_, kt + 5);
    COMPUTE(s2_, accA); LOADK(s2_, kt + 6);
    COMPUTE(s3_, accA);
  }
  for (int kt = 32; kt < 56; kt += 4) {  // k >= 1024 half -> accB
    LOADK(s3_, kt + 3);
    COMPUTE(s0_, accB); LOADK(s0_, kt + 4);
    COMPUTE(s1_, accB); LOADK(s1_, kt + 5);
    COMPUTE(s2_, accB); LOADK(s2_, kt + 6);
    COMPUTE(s3_, accB);
  }
  // kt=56 group with prefetch of 60..62, then the 60..63 peel (FIXED tail:
  // every kt 0..63 computed exactly once, in order).
  LOADK(s3_, 59);
  COMPUTE(s0_, accB); LOADK(s0_, 60);
  COMPUTE(s1_, accB); LOADK(s1_, 61);
  COMPUTE(s2_, accB); LOADK(s2_, 62);
  COMPUTE(s3_, accB);
  LOADK(s3_, 63);
  COMPUTE(s0_, accB); COMPUTE(s1_, accB); COMPUTE(s2_, accB);
  COMPUTE(s3_, accB);

  __syncthreads();  // only barrier before the epilogue

  // ---- fused epilogue: accumulators -> LDS P tile ----
#pragma unroll
  for (int mt = 0; mt < 2; ++mt)
#pragma unroll
    for (int nt = 0; nt < 2; ++nt)
#pragma unroll
      for (int rg = 0; rg < 4; ++rg)
        Ps[(mt * 16 + fq * 4 + rg) * 256 + wave * 32 + nt * 16 + frow] =
            accA[mt][nt][rg] + accB[mt][nt][rg];  // == (P0 + P1), same order as before
  __syncthreads();

  // sigmoid in place: thread owns column (tid&255), half the rows
  {
    int col = tid & 255;
    int r0 = (tid >> 8) * 16;
    float bc2 = bp[col], bec = betap[col];
#pragma unroll 4
    for (int i = r0; i < r0 + 16; ++i) {
      float v = Ps[i * 256 + col];
      Ps[i * 256 + col] = 1.f / (1.f + __expf(-bec * (v + bc2)));
    }
  }
  __syncthreads();

  // tree walk: wave handles rows wave*4 .. +4; node sums accumulated in regs
  float wdot = 0.f;
  float s0r[7] = {}, s1r[7] = {};
  for (int it = 0; it < 4; ++it) {
    int rl = wave * 4 + it;
    int r = m_base + rl;
    const float* wsp = Ps + rl * 256;
    int tg = tgt[r];
    float pp = 1.f;  // path product into current depth
#pragma unroll
    for (int d = 1; d <= 6; ++d) {
      int idx = (1 << (d - 1)) - 1 + (lane >> (7 - d));
      float p = wsp[idx];
      s0r[d - 1] += pp;       // only first covering lane's value is used later
      s1r[d - 1] += p * pp;
      pp *= ((lane >> (6 - d)) & 1) ? p : (1.f - p);
    }
    float p7 = wsp[63 + lane];
    s0r[6] += pp;
    s1r[6] += p7 * pp;
    float pL = pp * (1.f - p7), pR = pp * p7;
    float p8a = wsp[127 + 2 * lane], p8b = wsp[128 + 2 * lane];
    float lf0 = pL * (1.f - p8a), lf1 = pL * p8a;
    float lf2 = pR * (1.f - p8b), lf3 = pR * p8b;
    float4 lq = *(const float4*)(logQT + (size_t)tg * NPAD + lane * 4);
    wdot += lf0 * lq.x + lf1 * lq.y + lf2 * lq.z + lf3 * lq.w;
    float bv = lf0; int bi = 4 * lane;
    if (lf1 > bv) { bv = lf1; bi = 4 * lane + 1; }
    if (lf2 > bv) { bv = lf2; bi = 4 * lane + 2; }
    if (lf3 > bv) { bv = lf3; bi = 4 * lane + 3; }
    for (int off = 32; off; off >>= 1) {
      float ov = __shfl_down(bv, off);
      int oi = __shfl_down(bi, off);
      if (ov > bv || (ov == bv && oi < bi)) { bv = ov; bi = oi; }  // first-max tie-break
    }
    if (lane == 0) best[r] = bi;
  }
  // fold per-wave node sums into block LDS arrays
#pragma unroll
  for (int d = 1; d <= 6; ++d) {
    int idx = (1 << (d - 1)) - 1 + (lane >> (7 - d));
    if ((lane & ((1 << (7 - d)) - 1)) == 0) {
      atomicAdd(&s0s[idx], s0r[d - 1]);
      atomicAdd(&s1s[idx], s1r[d - 1]);
    }
  }
  atomicAdd(&s0s[63 + lane], s0r[6]);
  atomicAdd(&s1s[63 + lane], s1r[6]);
  for (int off = 32; off; off >>= 1) wdot += __shfl_down(wdot, off);
  if (lane == 0) atomicAdd(&sdot, wdot);
  __syncthreads();
  if (tid < 127) {
    atomicAdd(&acc[tid], s0s[tid]);
    atomicAdd(&acc[127 + tid], s1s[tid]);
  }
  if (tid == 255) atomicAdd(&acc[254], sdot);
}

// gather + loss in one launch: blocks 0..4095 gather rows, block 4096 = loss.
__global__ __launch_bounds__(256) void gather_loss(const float* __restrict__ Q,
                                                   const int* __restrict__ best,
                                                   const float* __restrict__ acc,
                                                   float* __restrict__ out) {
  if (blockIdx.x < 4096) {
    int wv = threadIdx.x >> 6, lane = threadIdx.x & 63;
    int r = blockIdx.x * 4 + wv;
    const float* src = Q + (size_t)best[r] * NCLS;
    float* dst = out + 1 + (size_t)r * NCLS;  // rows start at global index 1+1000r
    if (lane < 3) dst[lane] = src[lane];
    if (lane == 0) dst[999] = src[999];
#pragma unroll
    for (int i = 0; i < 4; ++i) {
      int q = i * 64 + lane;
      if (q < 249) {
        int o = 3 + 4 * q;  // 16B-aligned in dst
        float4 v = make_float4(src[o], src[o + 1], src[o + 2], src[o + 3]);
        *(float4*)(dst + o) = v;
      }
    }
  } else {
    // loss block (all 256 threads participate in the barriers)
    __shared__ float red[128];
    int t = threadIdx.x;
    float c = 0.f;
    if (t < 127) {
      float denom = acc[t];
      if (denom == 0.f) denom = 1e-6f;
      float alpha = acc[127 + t] / denom;
      alpha = fminf(fmaxf(alpha, 1e-6f), 1.f - 1e-6f);
      int d = 31 - __clz(t + 1) + 1;  // depth: idx 0 -> 1, idx 1..2 -> 2, ...
      float lm = 0.1f * exp2f(-(float)d);
      c = -lm * 0.5f * (logf(alpha) + log1pf(-alpha));
    }
    if (t < 128) red[t] = c;
    __syncthreads();
    for (int s = 64; s; s >>= 1) { if (t < s) red[t] += red[t + s]; __syncthreads(); }
    if (t == 0) out[0] = -(acc[254] / 16384.f) + red[0];
  }
}

extern "C" void kernel_launch(void* const* d_in, const int* in_sizes, int n_in,
                              void* d_out, int out_size, void* d_ws, size_t ws_size,
                              hipStream_t stream) {
  const float* x = (const float*)d_in[0];
  const float* y = (const float*)d_in[1];
  const float* W = (const float*)d_in[2];
  const float* b = (const float*)d_in[3];
  const float* beta = (const float*)d_in[4];
  const float* leaf = (const float*)d_in[5];
  float* out = (float*)d_out;
  char* ws = (char*)d_ws;

  unsigned short* WbP = (unsigned short*)(ws + 0);       // 1048576 (fragment-major)
  float* bp    = (float*)(ws + 1048576);                 // 1024
  float* betap = (float*)(ws + 1049600);                 // 1024
  float* accb  = (float*)(ws + 1050624);                 // 1024 (255 used)
  int* tgt     = (int*)(ws + 1051648);                   // 65536
  int* best    = (int*)(ws + 1117184);                   // 65536
  float* logQT = (float*)(ws + 1182720);                 // 1000*256*4 = 1024000
  float* Q     = (float*)(ws + 2206720);                 // 1024000
  unsigned short* xP = (unsigned short*)(ws + 4194304);  // 16384*2048*2 = 64 MB

  prep_all<<<8704, 256, 0, stream>>>(x, y, W, b, beta, leaf, WbP, xP, bp, betap,
                                     logQT, Q, tgt, accb);
  gemm_tree<<<512, 512, 0, stream>>>(xP, WbP, bp, betap, logQT, tgt, accb, best);
  gather_loss<<<4097, 256, 0, stream>>>(Q, best, accb, out);
}